// Round 10
// baseline (404.440 us; speedup 1.0000x reference)
//
#include <hip/hip_runtime.h>
#include <hip/hip_bf16.h>

typedef float f32x4 __attribute__((ext_vector_type(4)));
typedef int   i32x4 __attribute__((ext_vector_type(4)));
typedef __bf16 bf16x8 __attribute__((ext_vector_type(8)));
typedef unsigned short u16;
typedef unsigned short u16x4 __attribute__((ext_vector_type(4)));
typedef unsigned short u16x8 __attribute__((ext_vector_type(8)));

#define MAXE 32

// fp32 -> bf16 native RNE cvt (compiler emits v_cvt_pk_bf16_f32)
__device__ __forceinline__ u16 f2bf(float f) {
  __bf16 h = (__bf16)f;
  return __builtin_bit_cast(u16, h);
}

// async global->LDS, 16B per lane; LDS dest = wave-uniform base + lane*16.
typedef const __attribute__((address_space(1))) void GAS;
typedef __attribute__((address_space(3))) void LAS;
__device__ __forceinline__ void gl_lds16(const void* g, void* l) {
  __builtin_amdgcn_global_load_lds((GAS*)g, (LAS*)l, 16, 0, 0);
}

// inp fp32 -> bf16 pre-pass (~10 us)
__global__ __launch_bounds__(256)
void cvt_bf16(const float* __restrict__ in, u16* __restrict__ out, int n8) {
  int i = blockIdx.x * 256 + threadIdx.x;
  if (i < n8) {
    f32x4 a = *(const f32x4*)(in + (long long)i * 8);
    f32x4 b = *(const f32x4*)(in + (long long)i * 8 + 4);
    u16x8 r = { f2bf(a[0]), f2bf(a[1]), f2bf(a[2]), f2bf(a[3]),
                f2bf(b[0]), f2bf(b[1]), f2bf(b[2]), f2bf(b[3]) };
    *(u16x8*)(out + (long long)i * 8) = r;
  }
}

// shared expert-prefix lookup: batched loads + predicated register walk
__device__ __forceinline__ int expert_lookup(const int* counts, int E, int bm,
                                             int mt_in, int& row0, int& cnt, int& mt) {
  int cs[MAXE];
#pragma unroll
  for (int j = 0; j < MAXE / 4; ++j) {
    if (j * 4 + 3 < E) *(i32x4*)&cs[j * 4] = *(const i32x4*)(counts + j * 4);
    else {
#pragma unroll
      for (int q = 0; q < 4; ++q) cs[j*4+q] = (j*4+q < E) ? counts[j*4+q] : 0;
    }
  }
  int e = -1; row0 = 0; cnt = 0; mt = mt_in;
#pragma unroll
  for (int i = 0; i < MAXE; ++i) {
    if (i < E && e < 0) {
      int ntl = (cs[i] + bm - 1) / bm;
      if (mt < ntl) { e = i; cnt = cs[i]; }
      else { mt -= ntl; row0 += cs[i]; }
    }
  }
  return e;
}

// ============ GEMM1: 128x128, gload_lds, TRIPLE-buffer + counted vmcnt ============
// r9 model: the 4 row-tile sharers of each w1 panel run in lockstep -> all pay
// full HBM miss latency every K-step; 1-deep pipeline + vmcnt(0) drain exposes
// ~800ns/step. Fixes: (T4) stage tile kt+2, wait vmcnt(6) (never 0) across raw
// s_barriers -> ~2 steps of latency cover; (rotation) block starts K-loop at
// (y&3)*8 of 32 steps -> sharers de-phase, followers hit L3 not the MSHR.
__global__ __launch_bounds__(256)
void ffn_gemm1(const u16* __restrict__ Ain, const float* __restrict__ Bw,
               const float* __restrict__ bias, u16* __restrict__ Out,
               const int* __restrict__ counts, int E, int T, int N, int K)
{
#define G1BM 128
#define G1BN 128
#define G1BK 32
  int row0, cnt, mt;
  int e = expert_lookup(counts, E, G1BM, blockIdx.y, row0, cnt, mt);
  if (e < 0) return;
  int valid = cnt - mt * G1BM; if (valid > G1BM) valid = G1BM;
  row0 += mt * G1BM;
  const int n0 = blockIdx.x * G1BN;

  const float* Be = Bw + (long long)e * N * K;
  const float* be = bias + (long long)e * N;

  __shared__ u16  As[3][G1BM * G1BK];   // 8 KB per buf
  __shared__ float Bs[3][G1BN * G1BK];  // 16 KB per buf  -> 72 KB, 2 blk/CU

  const int t = threadIdx.x;
  const int lane = t & 63;
  const int w = t >> 6, wr = w >> 1, wc = w & 1;  // 2x2 waves -> 64x64
  const int NKT = K / G1BK;                        // 32
  const int rot = (blockIdx.y & 3) * 8;            // sharer de-phasing

  // staging descriptors (r8-proven). A: 2 shots/wave of 1KB (8B granules);
  // B: 4 shots/wave, source granule pre-swizzled p^(r&7) (rule 21).
  int aSrc[2], aDst[2];
#pragma unroll
  for (int s = 0; s < 2; ++s) {
    int rb = (s * 4 + w) * 16;
    int r = rb + (lane >> 2);
    int gr = row0 + r; if (gr > T - 1) gr = T - 1;
    aSrc[s] = gr * K + ((lane & 3) << 3);
    aDst[s] = rb * G1BK;
  }
  int bSrc[4], bDst[4];
#pragma unroll
  for (int s = 0; s < 4; ++s) {
    int rb = (s * 4 + w) * 8;
    int r = rb + (lane >> 3);
    bSrc[s] = (n0 + r) * K + (((lane & 7) ^ (r & 7)) << 2);
    bDst[s] = rb * G1BK;
  }

  auto stage = [&](int buf, int ktp) {
    const int k0 = ktp * G1BK;
#pragma unroll
    for (int s = 0; s < 2; ++s) gl_lds16(Ain + aSrc[s] + k0, &As[buf][aDst[s]]);
#pragma unroll
    for (int s = 0; s < 4; ++s) gl_lds16(Be + bSrc[s] + k0, &Bs[buf][bDst[s]]);
  };

  // fragment read offsets (K-invariant); B frag read undoes the src swizzle
  const int rl = lane & 15, kg = lane >> 4;
  int aoff[4], boff[4];
#pragma unroll
  for (int mf = 0; mf < 4; ++mf) {
    int R = wr * 64 + mf * 16 + rl;
    aoff[mf] = R * G1BK + kg * 8;
  }
#pragma unroll
  for (int nf = 0; nf < 4; ++nf) {
    int R = wc * 64 + nf * 16 + rl;
    int go = (2 * kg) ^ (R & 7);
    boff[nf] = R * G1BK + go * 4;
  }

  f32x4 acc[4][4];
#pragma unroll
  for (int i = 0; i < 4; ++i)
#pragma unroll
    for (int j = 0; j < 4; ++j) acc[i][j] = (f32x4){0.f, 0.f, 0.f, 0.f};

  // prologue: tiles 0,1 in flight; wait only tile 0 (vmcnt 12 -> 6)
  stage(0, rot % NKT);
  stage(1, (1 + rot) % NKT);
  asm volatile("s_waitcnt vmcnt(6)" ::: "memory");
  __builtin_amdgcn_s_barrier();
  __builtin_amdgcn_sched_barrier(0);

  for (int kt = 0; kt < NKT; ++kt) {
    const int cur = kt % 3;
    if (kt + 2 < NKT) stage((kt + 2) % 3, (kt + 2 + rot) % NKT);

    bf16x8 af[4], bfr[4];
#pragma unroll
    for (int mf = 0; mf < 4; ++mf)
      af[mf] = __builtin_bit_cast(bf16x8, *(const u16x8*)&As[cur][aoff[mf]]);
#pragma unroll
    for (int nf = 0; nf < 4; ++nf) {
      f32x4 lo = *(const f32x4*)&Bs[cur][boff[nf]];
      f32x4 hi = *(const f32x4*)&Bs[cur][boff[nf] ^ 4];
      u16x8 r = { f2bf(lo[0]), f2bf(lo[1]), f2bf(lo[2]), f2bf(lo[3]),
                  f2bf(hi[0]), f2bf(hi[1]), f2bf(hi[2]), f2bf(hi[3]) };
      bfr[nf] = __builtin_bit_cast(bf16x8, r);
    }

    __builtin_amdgcn_s_setprio(1);
#pragma unroll
    for (int mf = 0; mf < 4; ++mf)
#pragma unroll
      for (int nf = 0; nf < 4; ++nf)
        acc[mf][nf] = __builtin_amdgcn_mfma_f32_16x16x32_bf16(af[mf], bfr[nf], acc[mf][nf], 0, 0, 0);
    __builtin_amdgcn_s_setprio(0);

    if (kt + 1 < NKT) {
      // counted wait: tile kt+1's 6 loads done; kt+2's may stay in flight
      if (kt + 2 < NKT) asm volatile("s_waitcnt vmcnt(6)" ::: "memory");
      else              asm volatile("s_waitcnt vmcnt(0)" ::: "memory");
      __builtin_amdgcn_s_barrier();
      __builtin_amdgcn_sched_barrier(0);
    }
  }

  // epilogue: C/D col=lane&15, row=(lane>>4)*4+r [m89/m91]
  const int cl = lane & 15, rg = lane >> 4;
#pragma unroll
  for (int mf = 0; mf < 4; ++mf) {
#pragma unroll
    for (int nf = 0; nf < 4; ++nf) {
      int gcol = n0 + wc * 64 + nf * 16 + cl;
      float bv = be[gcol];
#pragma unroll
      for (int r = 0; r < 4; ++r) {
        int lrow = wr * 64 + mf * 16 + rg * 4 + r;
        if (lrow < valid) {
          float v = acc[mf][nf][r] + bv;
          v = 0.5f * v * (1.0f + erff(v * 0.70710678118654752f));
          Out[(long long)(row0 + lrow) * N + gcol] = f2bf(v);
        }
      }
    }
  }
}

// ============ GEMM2: r3 reg-staged 128x128 template (proven ~859 TF) ============
#define BM 128
#define BN 128
#define BK 32
#define NT 256

template<bool DO_GELU, bool OUT_BF16>
__global__ __launch_bounds__(NT)
void ffn_gemm(const u16* __restrict__ Ain, const float* __restrict__ Bw,
              const float* __restrict__ bias, void* __restrict__ Out,
              const int* __restrict__ counts, int E, int T, int N, int K)
{
  int row0, cnt, mt;
  int e = expert_lookup(counts, E, BM, blockIdx.y, row0, cnt, mt);
  if (e < 0) return;
  int valid = cnt - mt * BM; if (valid > BM) valid = BM;
  row0 += mt * BM;
  const int n0 = blockIdx.x * BN;

  const float* Be = Bw + (long long)e * N * K;
  const float* be = bias + (long long)e * N;

  __shared__ u16 As[2][BM][BK];
  __shared__ u16 Bs[2][BN][BK];

  const int t = threadIdx.x;
  const int lane = t & 63;
  const int w = t >> 6, wr = w >> 1, wc = w & 1;
  const int NKT = K / BK;

  long long offA[2];
#pragma unroll
  for (int i = 0; i < 2; ++i) {
    int c = i * NT + t;
    int row = c >> 2, col = (c & 3) << 3;
    int gr = row0 + row; if (gr > T - 1) gr = T - 1;
    offA[i] = (long long)gr * K + col;
  }
  long long offB[4];
#pragma unroll
  for (int i = 0; i < 4; ++i) {
    int c = i * NT + t;
    offB[i] = (long long)(n0 + (c >> 3)) * K + ((c & 7) << 2);
  }

  f32x4 acc[4][4];
#pragma unroll
  for (int i = 0; i < 4; ++i)
#pragma unroll
    for (int j = 0; j < 4; ++j) acc[i][j] = (f32x4){0.f, 0.f, 0.f, 0.f};

  u16x8 rAu[2]; float rB[16];

  auto load_g = [&](int kt) {
    const int k0 = kt * BK;
#pragma unroll
    for (int i = 0; i < 2; ++i)
      rAu[i] = *(const u16x8*)(Ain + offA[i] + k0);
#pragma unroll
    for (int i = 0; i < 4; ++i) {
      f32x4 v = *(const f32x4*)(Be + offB[i] + k0);
      rB[i*4+0] = v[0]; rB[i*4+1] = v[1]; rB[i*4+2] = v[2]; rB[i*4+3] = v[3];
    }
  };

  auto store_tile = [&](int buf) {
#pragma unroll
    for (int i = 0; i < 2; ++i) {
      int c = i * NT + t;
      int row = c >> 2, col = (c & 3) << 3;
      int kg2 = (col >> 3) ^ ((row >> 1) & 3);
      *(u16x8*)&As[buf][row][kg2 * 8] = rAu[i];
    }
#pragma unroll
    for (int i = 0; i < 4; ++i) {
      int c = i * NT + t;
      int row = c >> 3, col = (c & 7) << 2;
      int kg2 = (col >> 3) ^ ((row >> 1) & 3);
      int off = kg2 * 8 + ((col >> 2) & 1) * 4;
      u16x4 pk = { f2bf(rB[i*4+0]), f2bf(rB[i*4+1]), f2bf(rB[i*4+2]), f2bf(rB[i*4+3]) };
      *(u16x4*)&Bs[buf][row][off] = pk;
    }
  };

  load_g(0);
  store_tile(0);
  load_g(1);
  __syncthreads();

  const int rl = lane & 15;
  const int kgf = (lane >> 4) ^ ((rl >> 1) & 3);

  for (int kt = 0; kt < NKT; ++kt) {
    const int cur = kt & 1;

    bf16x8 af[4], bfr[4];
#pragma unroll
    for (int mf = 0; mf < 4; ++mf)
      af[mf] = __builtin_bit_cast(bf16x8, *(const u16x8*)&As[cur][wr*64 + mf*16 + rl][kgf*8]);
#pragma unroll
    for (int nf = 0; nf < 4; ++nf)
      bfr[nf] = __builtin_bit_cast(bf16x8, *(const u16x8*)&Bs[cur][wc*64 + nf*16 + rl][kgf*8]);

    if (kt + 1 < NKT) store_tile(cur ^ 1);
    if (kt + 2 < NKT) load_g(kt + 2);

#pragma unroll
    for (int mf = 0; mf < 4; ++mf)
#pragma unroll
      for (int nf = 0; nf < 4; ++nf)
        acc[mf][nf] = __builtin_amdgcn_mfma_f32_16x16x32_bf16(af[mf], bfr[nf], acc[mf][nf], 0, 0, 0);

    if (kt + 1 < NKT) __syncthreads();
  }

  const int cl = lane & 15, rg = lane >> 4;
#pragma unroll
  for (int mf = 0; mf < 4; ++mf) {
#pragma unroll
    for (int nf = 0; nf < 4; ++nf) {
      int gcol = n0 + wc*64 + nf*16 + cl;
      float bv = be[gcol];
#pragma unroll
      for (int r = 0; r < 4; ++r) {
        int lrow = wr*64 + mf*16 + rg*4 + r;
        if (lrow < valid) {
          float v = acc[mf][nf][r] + bv;
          if constexpr (DO_GELU)
            v = 0.5f * v * (1.0f + erff(v * 0.70710678118654752f));
          long long idx = (long long)(row0 + lrow) * N + gcol;
          if constexpr (OUT_BF16) ((u16*)Out)[idx] = f2bf(v);
          else                    ((float*)Out)[idx] = v;
        }
      }
    }
  }
}

extern "C" void kernel_launch(void* const* d_in, const int* in_sizes, int n_in,
                              void* d_out, int out_size, void* d_ws, size_t ws_size,
                              hipStream_t stream) {
  const float* inp = (const float*)d_in[0];
  const float* w1  = (const float*)d_in[1];
  const float* b1  = (const float*)d_in[2];
  const float* w2  = (const float*)d_in[3];
  const float* b2  = (const float*)d_in[4];
  const int* cnts  = (const int*)d_in[5];

  const int E = in_sizes[5];
  const int H = in_sizes[2] / E;       // 4096
  const int D = in_sizes[4] / E;       // 1024
  const int T = in_sizes[0] / D;       // 8192

  u16* hbuf = (u16*)d_ws;                                  // T*H bf16 (64 MB)
  u16* ibuf = (u16*)((char*)d_ws + (size_t)T * H * 2);     // T*D bf16 (16 MB)

  // 0) inp -> bf16
  const int n8 = (T * D) / 8;
  cvt_bf16<<<dim3((n8 + 255) / 256), dim3(256), 0, stream>>>(inp, ibuf, n8);

  const int tiles = T / BM + E;  // upper bound on row-tiles

  // 1) h = gelu(ibuf @ w1^T + b1) — triple-buffer + counted vmcnt + rotation
  dim3 g1(H / BN, tiles);
  ffn_gemm1<<<g1, dim3(NT), 0, stream>>>(ibuf, w1, b1, hbuf, cnts, E, T, H, D);

  // 2) out = hbuf @ w2^T + b2 — proven r3 template
  dim3 g2(D / BN, tiles);
  ffn_gemm<false, false><<<g2, dim3(NT), 0, stream>>>(
      hbuf, w2, b2, d_out, cnts, E, T, D, H);
}